// Round 7
// baseline (95.396 us; speedup 1.0000x reference)
//
#include <hip/hip_runtime.h>
#include <hip/hip_bf16.h>

typedef __bf16 bf16;
typedef __attribute__((ext_vector_type(4))) __bf16 bf16x4;
typedef __attribute__((ext_vector_type(8))) __bf16 bf16x8;
typedef __attribute__((ext_vector_type(4))) float f32x4;

#define SEQ   4096
#define DIMN  1024
#define NHEAD 8
#define HD    128
#define MALL  4160   /* 4096 X rows + 64 Cp rows */
#define PENV  -10000.0f
#define NT    16     /* K-tiles of 64 */

typedef const __attribute__((address_space(1))) void gvoid_t;
typedef __attribute__((address_space(3))) void lvoid_t;

// ---------------------------------------------------------------- cvt: fp32 -> bf16, X ++ Cp
__global__ __launch_bounds__(256) void cvt_cat_kernel(
    const float* __restrict__ X, const float* __restrict__ Cp, bf16* __restrict__ A) {
  int i = blockIdx.x * 256 + threadIdx.x;
  size_t base = (size_t)i * 4;
  if (base >= (size_t)MALL * DIMN) return;
  const float* src = (base < (size_t)SEQ * DIMN) ? (X + base) : (Cp + (base - (size_t)SEQ * DIMN));
  float4 v = *(const float4*)src;
  bf16x4 o;
  o[0] = (bf16)v.x; o[1] = (bf16)v.y; o[2] = (bf16)v.z; o[3] = (bf16)v.w;
  *(bf16x4*)&A[base] = o;
}

// ---------------------------------------------------------------- cvt+transpose W[k][n] -> Wt[n][k] bf16
__global__ __launch_bounds__(256) void cvt_trans_kernel(
    const float* __restrict__ W0, const float* __restrict__ W1, const float* __restrict__ W2,
    bf16* __restrict__ Wt) {
  const float* W = (blockIdx.z == 0) ? W0 : ((blockIdx.z == 1) ? W1 : W2);
  bf16* dst = Wt + (size_t)blockIdx.z * DIMN * DIMN;
  __shared__ bf16 tile[64][72];
  int k0 = blockIdx.y * 64, n0 = blockIdx.x * 64;
  int tx = threadIdx.x & 63, ty = threadIdx.x >> 6;
#pragma unroll
  for (int r = ty; r < 64; r += 4)
    tile[tx][r] = (bf16)W[(size_t)(k0 + r) * DIMN + n0 + tx];
  __syncthreads();
#pragma unroll
  for (int r = ty; r < 64; r += 4)
    dst[(size_t)(n0 + r) * DIMN + k0 + tx] = tile[r][tx];
}

// ---------------------------------------------------------------- fused QKV GEMM — m201 8-phase port.
// 256^2 tile, BK=64, dbuf-2, XOR chunk swizzle (source+read). 4 phases per K-tile:
// {ds_read frags | stage 2 gloads | barrier | lgkmcnt(0) | 16 MFMA | barrier}.
// Tile t staged across (t-2).P4 + (t-1).P1/P2/P3 into just-freed regions; buf-switch
// wait = vmcnt(2) at P4-end (counted, never 0 mid-loop).
// z = 0:Q [m][n], 1:K [m][n], 2:V stored TRANSPOSED VT[n][m].
__global__ __launch_bounds__(512) void gemm_qkv_kernel(
    const bf16* __restrict__ A, const bf16* __restrict__ Wt,
    const float* __restrict__ bQ, const float* __restrict__ bK, const float* __restrict__ bV,
    bf16* __restrict__ QKV) {
  const int z = blockIdx.z;
  const int M = (z == 0) ? SEQ : MALL;
  const int m0 = blockIdx.y * 256;
  if (m0 >= M) return;
  const int n0 = blockIdx.x * 256;
  const bf16* Wz = Wt + (size_t)z * DIMN * DIMN;
  const float* bias = (z == 0) ? bQ : ((z == 1) ? bK : bV);
  bf16* out = QKV + (size_t)z * MALL * DIMN;

  __shared__ bf16 Ab[2][256 * 64];   // 32 KiB each; linear rows of 64, chunk-XOR-swizzled
  __shared__ bf16 Bb[2][256 * 64];

  const int t = threadIdx.x;
  const int lane = t & 63, w = t >> 6;
  const int wm = w >> 2, wn = w & 3;          // 2 x 4 wave grid; per-wave output 128x64
  const int r16 = lane & 15, g4 = lane >> 4;

  f32x4 acc[8][4] = {};

  // Stage one A-quarter (64 rows x 64 cols, 8KB = 1 gload/thread) of tile kt.
  auto stageAq = [&](int kt, int qr) {
    int segBase = qr * 512 + w * 64;
    int seg = segBase + lane;
    int row = seg >> 3;
    int cc = (seg & 7) ^ (row & 7);           // source-side swizzle
    int gm = m0 + row; gm = (gm < M) ? gm : (M - 1);
    __builtin_amdgcn_global_load_lds(
        (gvoid_t*)(A + (size_t)gm * DIMN + kt * 64 + cc * 8),
        (lvoid_t*)(&Ab[kt & 1][segBase * 8]), 16, 0, 0);
  };
  auto stageBq = [&](int kt, int qr) {
    int segBase = qr * 512 + w * 64;
    int seg = segBase + lane;
    int row = seg >> 3;
    int cc = (seg & 7) ^ (row & 7);
    int gn = n0 + row;   // always < 1024
    __builtin_amdgcn_global_load_lds(
        (gvoid_t*)(Wz + (size_t)gn * DIMN + kt * 64 + cc * 8),
        (lvoid_t*)(&Bb[kt & 1][segBase * 8]), 16, 0, 0);
  };

  // Read-side swizzle matches source-side.
  auto rdA = [&](const bf16* Ax, int mf, int kk) -> bf16x8 {
    int row = wm * 128 + mf * 16 + r16;
    return *(const bf16x8*)&Ax[row * 64 + (((kk * 4 + g4) ^ (row & 7)) * 8)];
  };
  auto rdB = [&](const bf16* Bx, int nf, int kk) -> bf16x8 {
    int row = wn * 64 + nf * 16 + r16;
    return *(const bf16x8*)&Bx[row * 64 + (((kk * 4 + g4) ^ (row & 7)) * 8)];
  };

  // Prologue: tiles 0 and 1 fully staged; tile 0 resident, tile 1's 8 in flight.
#pragma unroll
  for (int qr = 0; qr < 4; ++qr) { stageAq(0, qr); stageBq(0, qr); }
#pragma unroll
  for (int qr = 0; qr < 4; ++qr) { stageAq(1, qr); stageBq(1, qr); }
  asm volatile("s_waitcnt vmcnt(8)" ::: "memory");
  __builtin_amdgcn_s_barrier();

  for (int kt = 0; kt < NT; ++kt) {
    const bf16* Ax = &Ab[kt & 1][0];
    const bf16* Bx = &Bb[kt & 1][0];
    bf16x8 aL[4], aH[4], bL[4];

    // ---------------- P1: MFMA acc[0..3] kk0
#pragma unroll
    for (int mf = 0; mf < 4; ++mf) aL[mf] = rdA(Ax, mf, 0);
#pragma unroll
    for (int nf = 0; nf < 4; ++nf) bL[nf] = rdB(Bx, nf, 0);
    if (kt >= 1 && kt + 1 < NT) { stageAq(kt + 1, 1); stageAq(kt + 1, 3); }  // aH regions of buf^1, freed at (kt-1).P4
    __builtin_amdgcn_s_barrier();
    asm volatile("s_waitcnt lgkmcnt(0)" ::: "memory");
    __builtin_amdgcn_sched_barrier(0);
    __builtin_amdgcn_s_setprio(1);
#pragma unroll
    for (int mf = 0; mf < 4; ++mf)
#pragma unroll
      for (int nf = 0; nf < 4; ++nf)
        acc[mf][nf] = __builtin_amdgcn_mfma_f32_16x16x32_bf16(aL[mf], bL[nf], acc[mf][nf], 0, 0, 0);
    __builtin_amdgcn_s_setprio(0);
    __builtin_amdgcn_s_barrier();

    // ---------------- P2: MFMA acc[4..7] kk0 (bL reused from registers)
#pragma unroll
    for (int mf = 0; mf < 4; ++mf) aH[mf] = rdA(Ax, 4 + mf, 0);
    if (kt >= 1 && kt + 1 < NT) { stageBq(kt + 1, 0); stageBq(kt + 1, 1); }  // B rows 0-127 of buf^1
    __builtin_amdgcn_s_barrier();
    asm volatile("s_waitcnt lgkmcnt(0)" ::: "memory");
    __builtin_amdgcn_sched_barrier(0);
    __builtin_amdgcn_s_setprio(1);
#pragma unroll
    for (int mf = 0; mf < 4; ++mf)
#pragma unroll
      for (int nf = 0; nf < 4; ++nf)
        acc[4 + mf][nf] = __builtin_amdgcn_mfma_f32_16x16x32_bf16(aH[mf], bL[nf], acc[4 + mf][nf], 0, 0, 0);
    __builtin_amdgcn_s_setprio(0);
    __builtin_amdgcn_s_barrier();

    // ---------------- P3: MFMA acc[0..3] kk1
    bf16x8 aL2[4], bL2[4];
#pragma unroll
    for (int mf = 0; mf < 4; ++mf) aL2[mf] = rdA(Ax, mf, 1);
#pragma unroll
    for (int nf = 0; nf < 4; ++nf) bL2[nf] = rdB(Bx, nf, 1);
    if (kt >= 1 && kt + 1 < NT) { stageBq(kt + 1, 2); stageBq(kt + 1, 3); }  // B rows 128-255
    __builtin_amdgcn_s_barrier();
    asm volatile("s_waitcnt lgkmcnt(0)" ::: "memory");
    __builtin_amdgcn_sched_barrier(0);
    __builtin_amdgcn_s_setprio(1);
#pragma unroll
    for (int mf = 0; mf < 4; ++mf)
#pragma unroll
      for (int nf = 0; nf < 4; ++nf)
        acc[mf][nf] = __builtin_amdgcn_mfma_f32_16x16x32_bf16(aL2[mf], bL2[nf], acc[mf][nf], 0, 0, 0);
    __builtin_amdgcn_s_setprio(0);
    __builtin_amdgcn_s_barrier();

    // ---------------- P4: MFMA acc[4..7] kk1
#pragma unroll
    for (int mf = 0; mf < 4; ++mf) aH[mf] = rdA(Ax, 4 + mf, 1);
    if (kt + 2 < NT) { stageAq(kt + 2, 0); stageAq(kt + 2, 2); }  // aL regions of THIS buf, freed after P3
    __builtin_amdgcn_s_barrier();
    asm volatile("s_waitcnt lgkmcnt(0)" ::: "memory");
    __builtin_amdgcn_sched_barrier(0);
    __builtin_amdgcn_s_setprio(1);
#pragma unroll
    for (int mf = 0; mf < 4; ++mf)
#pragma unroll
      for (int nf = 0; nf < 4; ++nf)
        acc[4 + mf][nf] = __builtin_amdgcn_mfma_f32_16x16x32_bf16(aH[mf], bL2[nf], acc[4 + mf][nf], 0, 0, 0);
    __builtin_amdgcn_s_setprio(0);

    // Buf-switch boundary: tile kt+1's 8 loads must be landed; tile kt+2's 2 (P4-issued)
    // stay in flight (counted vmcnt, never 0 mid-loop).
    if (kt + 1 < NT) {
      if (kt + 2 < NT) asm volatile("s_waitcnt vmcnt(2)" ::: "memory");
      else             asm volatile("s_waitcnt vmcnt(0)" ::: "memory");
      __builtin_amdgcn_s_barrier();
    }
  }

  // ---- epilogue
  if (z == 2) {
    // V: write TRANSPOSED VT[n][m]; each thread owns 4 consecutive m -> one 8B store.
#pragma unroll
    for (int nf = 0; nf < 4; ++nf) {
      int n = n0 + wn * 64 + nf * 16 + r16;
      float bv = bias[n];
#pragma unroll
      for (int mf = 0; mf < 8; ++mf) {
        int mbase = m0 + wm * 128 + mf * 16 + g4 * 4;
        if (mbase < M) {
          bf16x4 o;
#pragma unroll
          for (int r = 0; r < 4; ++r) o[r] = (bf16)(acc[mf][nf][r] + bv);
          *(bf16x4*)&out[(size_t)n * MALL + mbase] = o;
        }
      }
    }
  } else {
#pragma unroll
    for (int nf = 0; nf < 4; ++nf) {
      int n = n0 + wn * 64 + nf * 16 + r16;
      float bv = bias[n];
#pragma unroll
      for (int mf = 0; mf < 8; ++mf) {
        int mbase = m0 + wm * 128 + mf * 16 + g4 * 4;
#pragma unroll
        for (int r = 0; r < 4; ++r) {
          int m = mbase + r;
          if (m < M) out[(size_t)m * DIMN + n] = (bf16)(acc[mf][nf][r] + bv);
        }
      }
    }
  }
}

// ---------------------------------------------------------------- key slot -> global row map (band paths)
__device__ __forceinline__ int key_row_map(int qb, int tslot) {
  if (qb <= 1) return tslot;                                    // rows 0..255
  if (qb == 63) return (tslot < 64) ? tslot : (3840 + tslot);   // block0 then blocks 61..63
  return (tslot < 64) ? tslot : ((qb - 1) * 64 + (tslot - 64)); // block0 + 3-block window
}

// ---------------------------------------------------------------- fused attention (unchanged from R6)
__global__ __launch_bounds__(256) void attn_kernel(
    const bf16* __restrict__ Q, const bf16* __restrict__ K, const bf16* __restrict__ VT,
    const float* __restrict__ mask, float* __restrict__ out) {
  const int bid = blockIdx.x;
  const int h = bid & 7, qb = bid >> 3;
  const int t = threadIdx.x;
  const int lane = t & 63, w = t >> 6;
  const int c16 = lane & 15, g4 = lane >> 4;
  const float sl = exp2f(-(float)(h + 1));
  const float rsq = 0.088388347648318447f;  // 1/sqrt(128)

  __shared__ bf16 KB[2][64 * 128];  // 16 KiB ring buffers, chunk-XOR-swizzled contents
  __shared__ bf16 P[64][264];       // probabilities, bf16, padded

  bf16x8 qf[4];
  {
    int srow = qb * 64 + w * 16 + c16;
    const bf16* qp = Q + (size_t)srow * DIMN + h * HD + g4 * 8;
#pragma unroll
    for (int ks = 0; ks < 4; ++ks) qf[ks] = *(const bf16x8*)(qp + ks * 32);
  }
  int iq[4]; float mi[4];
#pragma unroll
  for (int r = 0; r < 4; ++r) { iq[r] = qb * 64 + w * 16 + g4 * 4 + r; mi[r] = mask[iq[r]]; }

  auto stageK = [&](int c) {
#pragma unroll
    for (int i = 0; i < 4; ++i) {
      int segBase = i * 256 + w * 64;
      int seg = segBase + lane;
      int kr = seg >> 4;
      int cc = (seg & 15) ^ (kr & 7);   // source-side swizzle
      int gr = (c == 4) ? (SEQ + kr) : key_row_map(qb, c * 64 + kr);
      __builtin_amdgcn_global_load_lds(
          (gvoid_t*)(K + (size_t)gr * DIMN + h * HD + cc * 8),
          (lvoid_t*)(&KB[c & 1][segBase * 8]), 16, 0, 0);
    }
  };

  f32x4 sc[16] = {};
  f32x4 sp[4] = {};

  stageK(0);
#pragma unroll
  for (int c = 0; c < 5; ++c) {
    if (c < 4) {
      stageK(c + 1);
      asm volatile("s_waitcnt vmcnt(4)" ::: "memory");
    } else {
      asm volatile("s_waitcnt vmcnt(0)" ::: "memory");
    }
    __builtin_amdgcn_s_barrier();
    const bf16* Kx = &KB[c & 1][0];
#pragma unroll
    for (int ks = 0; ks < 4; ++ks)
#pragma unroll
      for (int kj = 0; kj < 4; ++kj) {
        int row = kj * 16 + c16;
        bf16x8 bfr = *(const bf16x8*)&Kx[row * 128 + (((ks * 4 + g4) ^ (row & 7)) * 8)];
        if (c < 4)
          sc[c * 4 + kj] = __builtin_amdgcn_mfma_f32_16x16x32_bf16(qf[ks], bfr, sc[c * 4 + kj], 0, 0, 0);
        else
          sp[kj] = __builtin_amdgcn_mfma_f32_16x16x32_bf16(qf[ks], bfr, sp[kj], 0, 0, 0);
      }
    __builtin_amdgcn_s_barrier();
  }

  // --- bias (distance + mask penalties) — replicates reference quirks exactly
#pragma unroll
  for (int f = 0; f < 16; ++f) {
    int tslot = f * 16 + c16;
    int jrow = key_row_map(qb, tslot);
    float mj = mask[jrow];
    int jpos = (qb == 63) ? (3840 + tslot) : jrow;
    int ishift = (qb >= 2 && qb <= 62) ? 128 : 0;
#pragma unroll
    for (int r = 0; r < 4; ++r) {
      float raw = sc[f][r];
      float dist = sl * fabsf((float)(iq[r] - ishift - jpos));
      float s;
      if (qb <= 1)       s = raw * rsq - dist + (1.f - mi[r]) * PENV;
      else if (qb == 63) s = raw * rsq - dist;
      else {
        float pen = (tslot < 64) ? (1.f - mi[r]) * PENV : (1.f - mi[r] * mj) * PENV;
        s = (raw + pen) * rsq - dist;
      }
      sc[f][r] = s;
    }
  }

  // --- softmax over 256 keys, P -> LDS (wave-private rows)
#pragma unroll
  for (int r = 0; r < 4; ++r) {
    float m = -1e30f;
#pragma unroll
    for (int f = 0; f < 16; ++f) m = fmaxf(m, sc[f][r]);
#pragma unroll
    for (int d = 1; d < 16; d <<= 1) m = fmaxf(m, __shfl_xor(m, d));
    float s = 0.f;
#pragma unroll
    for (int f = 0; f < 16; ++f) { float e = __expf(sc[f][r] - m); sc[f][r] = e; s += e; }
#pragma unroll
    for (int d = 1; d < 16; d <<= 1) s += __shfl_xor(s, d);
    float inv = 1.0f / s;
#pragma unroll
    for (int f = 0; f < 16; ++f)
      P[w * 16 + g4 * 4 + r][f * 16 + c16] = (bf16)(sc[f][r] * inv);
  }

  // --- band PV from global VT
  f32x4 ctx[8] = {};
  const bf16* vt_h = VT + (size_t)h * HD * MALL;
#pragma unroll
  for (int c = 0; c < 4; ++c) {
    int kst = key_row_map(qb, c * 64);
#pragma unroll
    for (int ks = 0; ks < 2; ++ks) {
      bf16x8 pa = *(const bf16x8*)&P[w * 16 + c16][c * 64 + ks * 32 + g4 * 8];
#pragma unroll
      for (int df = 0; df < 8; ++df) {
        bf16x8 bv = *(const bf16x8*)&vt_h[(size_t)(df * 16 + c16) * MALL + kst + ks * 32 + g4 * 8];
        ctx[df] = __builtin_amdgcn_mfma_f32_16x16x32_bf16(pa, bv, ctx[df], 0, 0, 0);
      }
    }
  }

  // --- packed softmax + PV
#pragma unroll
  for (int r = 0; r < 4; ++r) {
    float m = -1e30f;
#pragma unroll
    for (int kj = 0; kj < 4; ++kj) m = fmaxf(m, sp[kj][r] * rsq);
#pragma unroll
    for (int d = 1; d < 16; d <<= 1) m = fmaxf(m, __shfl_xor(m, d));
    float s = 0.f;
    float e[4];
#pragma unroll
    for (int kj = 0; kj < 4; ++kj) { e[kj] = __expf(sp[kj][r] * rsq - m); s += e[kj]; }
#pragma unroll
    for (int d = 1; d < 16; d <<= 1) s += __shfl_xor(s, d);
    float inv = mi[r] / s;
#pragma unroll
    for (int kj = 0; kj < 4; ++kj)
      P[w * 16 + g4 * 4 + r][kj * 16 + c16] = (bf16)(e[kj] * inv);
  }
#pragma unroll
  for (int ks = 0; ks < 2; ++ks) {
    bf16x8 pa = *(const bf16x8*)&P[w * 16 + c16][ks * 32 + g4 * 8];
#pragma unroll
    for (int df = 0; df < 8; ++df) {
      bf16x8 bv = *(const bf16x8*)&vt_h[(size_t)(df * 16 + c16) * MALL + SEQ + ks * 32 + g4 * 8];
      ctx[df] = __builtin_amdgcn_mfma_f32_16x16x32_bf16(pa, bv, ctx[df], 0, 0, 0);
    }
  }

  // --- output
#pragma unroll
  for (int df = 0; df < 8; ++df) {
    int d = df * 16 + c16;
#pragma unroll
    for (int r = 0; r < 4; ++r) {
      int s = iq[r];
      float fm = mask[h * 512 + (s >> 3)];
      out[(size_t)h * (SEQ * HD) + (size_t)s * HD + d] = ctx[df][r] * fm;
    }
  }
}

// ---------------------------------------------------------------- launch
extern "C" void kernel_launch(void* const* d_in, const int* in_sizes, int n_in,
                              void* d_out, int out_size, void* d_ws, size_t ws_size,
                              hipStream_t stream) {
  const float* X    = (const float*)d_in[0];
  const float* Cp   = (const float*)d_in[1];
  const float* mask = (const float*)d_in[2];
  const float* WQ   = (const float*)d_in[3];
  const float* bQ   = (const float*)d_in[4];
  const float* WK   = (const float*)d_in[5];
  const float* bK   = (const float*)d_in[6];
  const float* WV   = (const float*)d_in[7];
  const float* bV   = (const float*)d_in[8];
  float* out = (float*)d_out;

  bf16* Abf = (bf16*)d_ws;                              // [4160][1024]
  bf16* Wt  = Abf + (size_t)MALL * DIMN;                // 3 x [1024][1024] (transposed)
  bf16* QKV = Wt + (size_t)3 * DIMN * DIMN;             // q[4160][1024], k[4160][1024], VT[1024][4160]

  int nCvt = (MALL * DIMN / 4 + 255) / 256;
  cvt_cat_kernel<<<nCvt, 256, 0, stream>>>(X, Cp, Abf);
  cvt_trans_kernel<<<dim3(16, 16, 3), 256, 0, stream>>>(WQ, WK, WV, Wt);
  gemm_qkv_kernel<<<dim3(4, 17, 3), 512, 0, stream>>>(Abf, Wt, bQ, bK, bV, QKV);
  attn_kernel<<<512, 256, 0, stream>>>(QKV, QKV + (size_t)MALL * DIMN,
                                       QKV + (size_t)2 * MALL * DIMN, mask, out);
}

// Round 8
// 93.189 us; speedup vs baseline: 1.0237x; 1.0237x over previous
//
#include <hip/hip_runtime.h>
#include <hip/hip_bf16.h>

typedef __bf16 bf16;
typedef __attribute__((ext_vector_type(4))) __bf16 bf16x4;
typedef __attribute__((ext_vector_type(8))) __bf16 bf16x8;
typedef __attribute__((ext_vector_type(4))) float f32x4;

#define SEQ   4096
#define DIMN  1024
#define NHEAD 8
#define HD    128
#define MALL  4160   /* 4096 X rows + 64 Cp rows */
#define PENV  -10000.0f
#define NT    16     /* K-tiles of 64 */

typedef const __attribute__((address_space(1))) void gvoid_t;
typedef __attribute__((address_space(3))) void lvoid_t;

// ---------------------------------------------------------------- cvt: fp32 -> bf16, X ++ Cp
__global__ __launch_bounds__(256) void cvt_cat_kernel(
    const float* __restrict__ X, const float* __restrict__ Cp, bf16* __restrict__ A) {
  int i = blockIdx.x * 256 + threadIdx.x;
  size_t base = (size_t)i * 4;
  if (base >= (size_t)MALL * DIMN) return;
  const float* src = (base < (size_t)SEQ * DIMN) ? (X + base) : (Cp + (base - (size_t)SEQ * DIMN));
  float4 v = *(const float4*)src;
  bf16x4 o;
  o[0] = (bf16)v.x; o[1] = (bf16)v.y; o[2] = (bf16)v.z; o[3] = (bf16)v.w;
  *(bf16x4*)&A[base] = o;
}

// ---------------------------------------------------------------- cvt+transpose W[k][n] -> Wt[n][k] bf16
__global__ __launch_bounds__(256) void cvt_trans_kernel(
    const float* __restrict__ W0, const float* __restrict__ W1, const float* __restrict__ W2,
    bf16* __restrict__ Wt) {
  const float* W = (blockIdx.z == 0) ? W0 : ((blockIdx.z == 1) ? W1 : W2);
  bf16* dst = Wt + (size_t)blockIdx.z * DIMN * DIMN;
  __shared__ bf16 tile[64][72];
  int k0 = blockIdx.y * 64, n0 = blockIdx.x * 64;
  int tx = threadIdx.x & 63, ty = threadIdx.x >> 6;
#pragma unroll
  for (int r = ty; r < 64; r += 4)
    tile[tx][r] = (bf16)W[(size_t)(k0 + r) * DIMN + n0 + tx];
  __syncthreads();
#pragma unroll
  for (int r = ty; r < 64; r += 4)
    dst[(size_t)(n0 + r) * DIMN + k0 + tx] = tile[r][tx];
}

// ---------------------------------------------------------------- fused QKV GEMM — occupancy-first.
// 128^2 tile, 4 waves (2x2, per-wave 64x64), BK=64, dbuf-2 (64 KiB LDS -> 2 blocks/CU),
// fused N=3072 (grid.x = 24 n-tiles; z = nt>>3). 792 blocks fill all 256 CUs ~3x.
// Minimal 2-barrier counted-vmcnt schedule; XOR chunk swizzle source+read (rule #21).
// z = 0:Q [m][n], 1:K [m][n], 2:V stored TRANSPOSED VT[n][m].
__global__ __launch_bounds__(256) void gemm_qkv_kernel(
    const bf16* __restrict__ A, const bf16* __restrict__ Wt,
    const float* __restrict__ bQ, const float* __restrict__ bK, const float* __restrict__ bV,
    bf16* __restrict__ QKV) {
  const int nt = blockIdx.x;            // 0..23
  const int z = nt >> 3;
  const int n0 = (nt & 7) * 128;
  const int m0 = blockIdx.y * 128;
  const int M = (z == 0) ? SEQ : MALL;
  if (m0 >= M) return;
  const bf16* Wz = Wt + (size_t)z * DIMN * DIMN;
  const float* bias = (z == 0) ? bQ : ((z == 1) ? bK : bV);
  bf16* out = QKV + (size_t)z * MALL * DIMN;

  __shared__ bf16 Ab[2][128 * 64];   // 16 KiB each; linear rows of 64, chunk-XOR-swizzled
  __shared__ bf16 Bb[2][128 * 64];

  const int t = threadIdx.x;
  const int lane = t & 63, w = t >> 6;
  const int wm = w >> 1, wn = w & 1;          // 2x2 wave grid; per-wave 64x64
  const int r16 = lane & 15, g4 = lane >> 4;

  f32x4 acc[4][4] = {};

  // Stage tile kt (A 128x64 + B 128x64 = 8 gloads/thread).
  auto stageT = [&](int kt) {
    int b = kt & 1;
#pragma unroll
    for (int i = 0; i < 4; ++i) {
      int segBase = i * 256 + w * 64;
      int seg = segBase + lane;
      int row = seg >> 3;
      int cc = (seg & 7) ^ (row & 7);         // source-side swizzle
      int gm = m0 + row; gm = (gm < M) ? gm : (M - 1);
      __builtin_amdgcn_global_load_lds(
          (gvoid_t*)(A + (size_t)gm * DIMN + kt * 64 + cc * 8),
          (lvoid_t*)(&Ab[b][segBase * 8]), 16, 0, 0);
    }
#pragma unroll
    for (int i = 0; i < 4; ++i) {
      int segBase = i * 256 + w * 64;
      int seg = segBase + lane;
      int row = seg >> 3;
      int cc = (seg & 7) ^ (row & 7);
      int gn = n0 + row;                      // always < 1024
      __builtin_amdgcn_global_load_lds(
          (gvoid_t*)(Wz + (size_t)gn * DIMN + kt * 64 + cc * 8),
          (lvoid_t*)(&Bb[b][segBase * 8]), 16, 0, 0);
    }
  };

  auto rdA = [&](const bf16* Ax, int mf, int kk) -> bf16x8 {
    int row = wm * 64 + mf * 16 + r16;
    return *(const bf16x8*)&Ax[row * 64 + (((kk * 4 + g4) ^ (row & 7)) * 8)];
  };
  auto rdB = [&](const bf16* Bx, int nf, int kk) -> bf16x8 {
    int row = wn * 64 + nf * 16 + r16;
    return *(const bf16x8*)&Bx[row * 64 + (((kk * 4 + g4) ^ (row & 7)) * 8)];
  };

  stageT(0);
  for (int kt = 0; kt < NT; ++kt) {
    // Ledger: top-of-kt outstanding = kt's 8 (issued prev iter / prologue).
    if (kt + 1 < NT) {
      stageT(kt + 1);                                    // outstanding 16
      asm volatile("s_waitcnt vmcnt(8)" ::: "memory");   // kt's 8 landed; kt+1's fly
    } else {
      asm volatile("s_waitcnt vmcnt(0)" ::: "memory");
    }
    __builtin_amdgcn_s_barrier();                        // all waves' kt stages visible
    const bf16* Ax = &Ab[kt & 1][0];
    const bf16* Bx = &Bb[kt & 1][0];
    bf16x8 a0[4], b0[4], a1[4], b1[4];
#pragma unroll
    for (int mf = 0; mf < 4; ++mf) a0[mf] = rdA(Ax, mf, 0);
#pragma unroll
    for (int nf = 0; nf < 4; ++nf) b0[nf] = rdB(Bx, nf, 0);
#pragma unroll
    for (int mf = 0; mf < 4; ++mf) a1[mf] = rdA(Ax, mf, 1);
#pragma unroll
    for (int nf = 0; nf < 4; ++nf) b1[nf] = rdB(Bx, nf, 1);
    asm volatile("s_waitcnt lgkmcnt(8)" ::: "memory");   // kk0 frags done; kk1 reads fly
    __builtin_amdgcn_sched_barrier(0);
    __builtin_amdgcn_s_setprio(1);
#pragma unroll
    for (int mf = 0; mf < 4; ++mf)
#pragma unroll
      for (int nf = 0; nf < 4; ++nf)
        acc[mf][nf] = __builtin_amdgcn_mfma_f32_16x16x32_bf16(a0[mf], b0[nf], acc[mf][nf], 0, 0, 0);
    __builtin_amdgcn_s_setprio(0);
    asm volatile("s_waitcnt lgkmcnt(0)" ::: "memory");
    __builtin_amdgcn_sched_barrier(0);
    __builtin_amdgcn_s_setprio(1);
#pragma unroll
    for (int mf = 0; mf < 4; ++mf)
#pragma unroll
      for (int nf = 0; nf < 4; ++nf)
        acc[mf][nf] = __builtin_amdgcn_mfma_f32_16x16x32_bf16(a1[mf], b1[nf], acc[mf][nf], 0, 0, 0);
    __builtin_amdgcn_s_setprio(0);
    __builtin_amdgcn_s_barrier();    // all waves done reading buf before next restage
  }

  // ---- epilogue
  if (z == 2) {
    // V: write TRANSPOSED VT[n][m]; each thread owns 4 consecutive m -> one 8B store.
#pragma unroll
    for (int nf = 0; nf < 4; ++nf) {
      int n = n0 + wn * 64 + nf * 16 + r16;
      float bv = bias[n];
#pragma unroll
      for (int mf = 0; mf < 4; ++mf) {
        int mbase = m0 + wm * 64 + mf * 16 + g4 * 4;
        if (mbase < M) {
          bf16x4 o;
#pragma unroll
          for (int r = 0; r < 4; ++r) o[r] = (bf16)(acc[mf][nf][r] + bv);
          *(bf16x4*)&out[(size_t)n * MALL + mbase] = o;
        }
      }
    }
  } else {
#pragma unroll
    for (int nf = 0; nf < 4; ++nf) {
      int n = n0 + wn * 64 + nf * 16 + r16;
      float bv = bias[n];
#pragma unroll
      for (int mf = 0; mf < 4; ++mf) {
        int mbase = m0 + wm * 64 + mf * 16 + g4 * 4;
#pragma unroll
        for (int r = 0; r < 4; ++r) {
          int m = mbase + r;
          if (m < M) out[(size_t)m * DIMN + n] = (bf16)(acc[mf][nf][r] + bv);
        }
      }
    }
  }
}

// ---------------------------------------------------------------- key slot -> global row map (band paths)
__device__ __forceinline__ int key_row_map(int qb, int tslot) {
  if (qb <= 1) return tslot;                                    // rows 0..255
  if (qb == 63) return (tslot < 64) ? tslot : (3840 + tslot);   // block0 then blocks 61..63
  return (tslot < 64) ? tslot : ((qb - 1) * 64 + (tslot - 64)); // block0 + 3-block window
}

// ---------------------------------------------------------------- fused attention — full LDS pipeline.
// Flat 512-block grid (all resident at 2 blocks/CU), h=bid&7. 4 waves x 16 queries.
// 10-chunk counted-vmcnt ring: chunks 0..4 = K tiles [64][128] (QK^T), 5..9 = V^T slabs
// [128][64] from VT (PV B-operand layout natively). Band+packed softmax overlaps the
// V0/V1 stage latency. NO global loads inside any MFMA chain.
__global__ __launch_bounds__(256) void attn_kernel(
    const bf16* __restrict__ Q, const bf16* __restrict__ K, const bf16* __restrict__ VT,
    const float* __restrict__ mask, float* __restrict__ out) {
  const int bid = blockIdx.x;
  const int h = bid & 7, qb = bid >> 3;
  const int t = threadIdx.x;
  const int lane = t & 63, w = t >> 6;
  const int c16 = lane & 15, g4 = lane >> 4;
  const float sl = exp2f(-(float)(h + 1));
  const float rsq = 0.088388347648318447f;  // 1/sqrt(128)

  __shared__ bf16 KB[2][8192];   // 16 KiB ring buffers (K tile or V^T slab), swizzled contents
  __shared__ bf16 P[64][328];    // band P cols 0..255, packed P cols 256..319 (+8 pad)

  bf16x8 qf[4];
  {
    int srow = qb * 64 + w * 16 + c16;
    const bf16* qp = Q + (size_t)srow * DIMN + h * HD + g4 * 8;
#pragma unroll
    for (int ks = 0; ks < 4; ++ks) qf[ks] = *(const bf16x8*)(qp + ks * 32);
  }
  int iq[4]; float mi[4];
#pragma unroll
  for (int r = 0; r < 4; ++r) { iq[r] = qb * 64 + w * 16 + g4 * 4 + r; mi[r] = mask[iq[r]]; }

  const bf16* vt_h = VT + (size_t)h * HD * MALL;

  // Stage chunk c: 4 gloads/thread, 16 KiB. c<5: K rows; c>=5: V^T d-rows (j=c-5).
  auto stageC = [&](int c) {
    int b = c & 1;
    if (c < 5) {
#pragma unroll
      for (int i = 0; i < 4; ++i) {
        int segBase = i * 256 + w * 64;
        int seg = segBase + lane;
        int kr = seg >> 4;
        int cc = (seg & 15) ^ (kr & 7);   // source-side swizzle
        int gr = (c == 4) ? (SEQ + kr) : key_row_map(qb, c * 64 + kr);
        __builtin_amdgcn_global_load_lds(
            (gvoid_t*)(K + (size_t)gr * DIMN + h * HD + cc * 8),
            (lvoid_t*)(&KB[b][segBase * 8]), 16, 0, 0);
      }
    } else {
      int j = c - 5;
      int colbase = (j == 4) ? SEQ : key_row_map(qb, j * 64);  // all chunks are 64 contiguous rows
#pragma unroll
      for (int i = 0; i < 4; ++i) {
        int segBase = i * 256 + w * 64;
        int seg = segBase + lane;
        int dr = seg >> 3;
        int cc = (seg & 7) ^ (dr & 7);
        __builtin_amdgcn_global_load_lds(
            (gvoid_t*)(vt_h + (size_t)dr * MALL + colbase + cc * 8),
            (lvoid_t*)(&KB[b][segBase * 8]), 16, 0, 0);
      }
    }
  };

  f32x4 sc[16] = {};
  f32x4 sp[4] = {};

  // ---- QK^T over 5 K-chunks (4 band + packed), distance-1 prefetch, counted vmcnt.
  stageC(0);
#pragma unroll
  for (int c = 0; c < 5; ++c) {
    stageC(c + 1);                                     // c=4 stages V0 -> covered by softmax
    asm volatile("s_waitcnt vmcnt(4)" ::: "memory");   // chunk c resident; c+1 flies
    __builtin_amdgcn_s_barrier();
    const bf16* Kx = &KB[c & 1][0];
#pragma unroll
    for (int ks = 0; ks < 4; ++ks)
#pragma unroll
      for (int kj = 0; kj < 4; ++kj) {
        int row = kj * 16 + c16;
        bf16x8 bfr = *(const bf16x8*)&Kx[row * 128 + (((ks * 4 + g4) ^ (row & 7)) * 8)];
        if (c < 4)
          sc[c * 4 + kj] = __builtin_amdgcn_mfma_f32_16x16x32_bf16(qf[ks], bfr, sc[c * 4 + kj], 0, 0, 0);
        else
          sp[kj] = __builtin_amdgcn_mfma_f32_16x16x32_bf16(qf[ks], bfr, sp[kj], 0, 0, 0);
      }
    __builtin_amdgcn_s_barrier();   // all waves done reading KB[c&1] before restage
  }

  // ---- bias (distance + mask penalties) — replicates reference quirks exactly
#pragma unroll
  for (int f = 0; f < 16; ++f) {
    int tslot = f * 16 + c16;
    int jrow = key_row_map(qb, tslot);
    float mj = mask[jrow];
    int jpos = (qb == 63) ? (3840 + tslot) : jrow;
    int ishift = (qb >= 2 && qb <= 62) ? 128 : 0;
#pragma unroll
    for (int r = 0; r < 4; ++r) {
      float raw = sc[f][r];
      float dist = sl * fabsf((float)(iq[r] - ishift - jpos));
      float s;
      if (qb <= 1)       s = raw * rsq - dist + (1.f - mi[r]) * PENV;
      else if (qb == 63) s = raw * rsq - dist;
      else {
        float pen = (tslot < 64) ? (1.f - mi[r]) * PENV : (1.f - mi[r] * mj) * PENV;
        s = (raw + pen) * rsq - dist;
      }
      sc[f][r] = s;
    }
  }

  // ---- band softmax (256 keys) -> P cols 0..255 (wave-private rows)
#pragma unroll
  for (int r = 0; r < 4; ++r) {
    float m = -1e30f;
#pragma unroll
    for (int f = 0; f < 16; ++f) m = fmaxf(m, sc[f][r]);
#pragma unroll
    for (int d = 1; d < 16; d <<= 1) m = fmaxf(m, __shfl_xor(m, d));
    float s = 0.f;
#pragma unroll
    for (int f = 0; f < 16; ++f) { float e = __expf(sc[f][r] - m); sc[f][r] = e; s += e; }
#pragma unroll
    for (int d = 1; d < 16; d <<= 1) s += __shfl_xor(s, d);
    float inv = 1.0f / s;
#pragma unroll
    for (int f = 0; f < 16; ++f)
      P[w * 16 + g4 * 4 + r][f * 16 + c16] = (bf16)(sc[f][r] * inv);
  }
  // ---- packed softmax (64 keys; constants cancel) -> P cols 256..319
#pragma unroll
  for (int r = 0; r < 4; ++r) {
    float m = -1e30f;
#pragma unroll
    for (int kj = 0; kj < 4; ++kj) m = fmaxf(m, sp[kj][r] * rsq);
#pragma unroll
    for (int d = 1; d < 16; d <<= 1) m = fmaxf(m, __shfl_xor(m, d));
    float s = 0.f;
    float e[4];
#pragma unroll
    for (int kj = 0; kj < 4; ++kj) { e[kj] = __expf(sp[kj][r] * rsq - m); s += e[kj]; }
#pragma unroll
    for (int d = 1; d < 16; d <<= 1) s += __shfl_xor(s, d);
    float inv = mi[r] / s;  // packed context pre-scaled by mask_v
#pragma unroll
    for (int kj = 0; kj < 4; ++kj)
      P[w * 16 + g4 * 4 + r][256 + kj * 16 + c16] = (bf16)(e[kj] * inv);
  }

  // ---- PV over 5 V-chunks (4 band + packed) through the same ring.
  f32x4 ctx[8] = {};
#pragma unroll
  for (int j = 0; j < 5; ++j) {
    int c = j + 5;
    if (c < 9) {
      stageC(c + 1);
      asm volatile("s_waitcnt vmcnt(4)" ::: "memory");
    } else {
      asm volatile("s_waitcnt vmcnt(0)" ::: "memory");
    }
    __builtin_amdgcn_s_barrier();
    const bf16* Vx = &KB[c & 1][0];
#pragma unroll
    for (int ks = 0; ks < 2; ++ks) {
      bf16x8 pa = *(const bf16x8*)&P[w * 16 + c16][j * 64 + ks * 32 + g4 * 8];
#pragma unroll
      for (int df = 0; df < 8; ++df) {
        int row = df * 16 + c16;
        bf16x8 bv = *(const bf16x8*)&Vx[row * 64 + (((ks * 4 + g4) ^ (row & 7)) * 8)];
        ctx[df] = __builtin_amdgcn_mfma_f32_16x16x32_bf16(pa, bv, ctx[df], 0, 0, 0);
      }
    }
    __builtin_amdgcn_s_barrier();
  }

  // ---- output: raw [H,S,hd] flatten; final mask uses reshaped-row quirk mask[h*512 + s/8]
#pragma unroll
  for (int df = 0; df < 8; ++df) {
    int d = df * 16 + c16;
#pragma unroll
    for (int r = 0; r < 4; ++r) {
      int s = iq[r];
      float fm = mask[h * 512 + (s >> 3)];
      out[(size_t)h * (SEQ * HD) + (size_t)s * HD + d] = ctx[df][r] * fm;
    }
  }
}

// ---------------------------------------------------------------- launch
extern "C" void kernel_launch(void* const* d_in, const int* in_sizes, int n_in,
                              void* d_out, int out_size, void* d_ws, size_t ws_size,
                              hipStream_t stream) {
  const float* X    = (const float*)d_in[0];
  const float* Cp   = (const float*)d_in[1];
  const float* mask = (const float*)d_in[2];
  const float* WQ   = (const float*)d_in[3];
  const float* bQ   = (const float*)d_in[4];
  const float* WK   = (const float*)d_in[5];
  const float* bK   = (const float*)d_in[6];
  const float* WV   = (const float*)d_in[7];
  const float* bV   = (const float*)d_in[8];
  float* out = (float*)d_out;

  bf16* Abf = (bf16*)d_ws;                              // [4160][1024]
  bf16* Wt  = Abf + (size_t)MALL * DIMN;                // 3 x [1024][1024] (transposed)
  bf16* QKV = Wt + (size_t)3 * DIMN * DIMN;             // q[4160][1024], k[4160][1024], VT[1024][4160]

  int nCvt = (MALL * DIMN / 4 + 255) / 256;
  cvt_cat_kernel<<<nCvt, 256, 0, stream>>>(X, Cp, Abf);
  cvt_trans_kernel<<<dim3(16, 16, 3), 256, 0, stream>>>(WQ, WK, WV, Wt);
  gemm_qkv_kernel<<<dim3(24, 33), 256, 0, stream>>>(Abf, Wt, bQ, bK, bV, QKV);
  attn_kernel<<<512, 256, 0, stream>>>(QKV, QKV + (size_t)MALL * DIMN,
                                       QKV + (size_t)2 * MALL * DIMN, mask, out);
}

// Round 9
// 89.602 us; speedup vs baseline: 1.0647x; 1.0400x over previous
//
#include <hip/hip_runtime.h>
#include <hip/hip_bf16.h>

typedef __bf16 bf16;
typedef __attribute__((ext_vector_type(4))) __bf16 bf16x4;
typedef __attribute__((ext_vector_type(8))) __bf16 bf16x8;
typedef __attribute__((ext_vector_type(4))) float f32x4;

#define SEQ   4096
#define DIMN  1024
#define NHEAD 8
#define HD    128
#define MALL  4160   /* 4096 X rows + 64 Cp rows */
#define PENV  -10000.0f
#define NT    16     /* K-tiles of 64 */

typedef const __attribute__((address_space(1))) void gvoid_t;
typedef __attribute__((address_space(3))) void lvoid_t;

// ---------------------------------------------------------------- cvt: fp32 -> bf16, X ++ Cp
__global__ __launch_bounds__(256) void cvt_cat_kernel(
    const float* __restrict__ X, const float* __restrict__ Cp, bf16* __restrict__ A) {
  int i = blockIdx.x * 256 + threadIdx.x;
  size_t base = (size_t)i * 4;
  if (base >= (size_t)MALL * DIMN) return;
  const float* src = (base < (size_t)SEQ * DIMN) ? (X + base) : (Cp + (base - (size_t)SEQ * DIMN));
  float4 v = *(const float4*)src;
  bf16x4 o;
  o[0] = (bf16)v.x; o[1] = (bf16)v.y; o[2] = (bf16)v.z; o[3] = (bf16)v.w;
  *(bf16x4*)&A[base] = o;
}

// ---------------------------------------------------------------- cvt+transpose W[k][n] -> Wt[n][k] bf16
__global__ __launch_bounds__(256) void cvt_trans_kernel(
    const float* __restrict__ W0, const float* __restrict__ W1, const float* __restrict__ W2,
    bf16* __restrict__ Wt) {
  const float* W = (blockIdx.z == 0) ? W0 : ((blockIdx.z == 1) ? W1 : W2);
  bf16* dst = Wt + (size_t)blockIdx.z * DIMN * DIMN;
  __shared__ bf16 tile[64][72];
  int k0 = blockIdx.y * 64, n0 = blockIdx.x * 64;
  int tx = threadIdx.x & 63, ty = threadIdx.x >> 6;
#pragma unroll
  for (int r = ty; r < 64; r += 4)
    tile[tx][r] = (bf16)W[(size_t)(k0 + r) * DIMN + n0 + tx];
  __syncthreads();
#pragma unroll
  for (int r = ty; r < 64; r += 4)
    dst[(size_t)(n0 + r) * DIMN + k0 + tx] = tile[r][tx];
}

// ---------------------------------------------------------------- fused QKV GEMM — R6 structure (best measured).
// 256^2 tile, BK=64, dbuf-2, XOR chunk swizzle (source+read), 4 pipelined sub-phases per tile.
// z = 0:Q [m][n], 1:K [m][n], 2:V stored TRANSPOSED VT[n][m].
__global__ __launch_bounds__(512) void gemm_qkv_kernel(
    const bf16* __restrict__ A, const bf16* __restrict__ Wt,
    const float* __restrict__ bQ, const float* __restrict__ bK, const float* __restrict__ bV,
    bf16* __restrict__ QKV) {
  const int z = blockIdx.z;
  const int M = (z == 0) ? SEQ : MALL;
  const int m0 = blockIdx.y * 256;
  if (m0 >= M) return;
  const int n0 = blockIdx.x * 256;
  const bf16* Wz = Wt + (size_t)z * DIMN * DIMN;
  const float* bias = (z == 0) ? bQ : ((z == 1) ? bK : bV);
  bf16* out = QKV + (size_t)z * MALL * DIMN;

  __shared__ bf16 Ab[2][256 * 64];
  __shared__ bf16 Bb[2][256 * 64];

  const int t = threadIdx.x;
  const int lane = t & 63, w = t >> 6;
  const int wm = w >> 2, wn = w & 3;
  const int r16 = lane & 15, g4 = lane >> 4;

  f32x4 acc[8][4] = {};

  auto stageA = [&](int k) {
    int b = k & 1;
#pragma unroll
    for (int i = 0; i < 4; ++i) {
      int segBase = i * 512 + w * 64;
      int seg = segBase + lane;
      int row = seg >> 3;
      int cc = (seg & 7) ^ (row & 7);
      int gm = m0 + row; gm = (gm < M) ? gm : (M - 1);
      __builtin_amdgcn_global_load_lds(
          (gvoid_t*)(A + (size_t)gm * DIMN + k * 64 + cc * 8),
          (lvoid_t*)(&Ab[b][segBase * 8]), 16, 0, 0);
    }
  };
  auto stageB = [&](int k) {
    int b = k & 1;
#pragma unroll
    for (int i = 0; i < 4; ++i) {
      int segBase = i * 512 + w * 64;
      int seg = segBase + lane;
      int row = seg >> 3;
      int cc = (seg & 7) ^ (row & 7);
      int gn = n0 + row;
      __builtin_amdgcn_global_load_lds(
          (gvoid_t*)(Wz + (size_t)gn * DIMN + k * 64 + cc * 8),
          (lvoid_t*)(&Bb[b][segBase * 8]), 16, 0, 0);
    }
  };

  auto rdA = [&](const bf16* Ax, int mf, int kk) -> bf16x8 {
    int row = wm * 128 + mf * 16 + r16;
    return *(const bf16x8*)&Ax[row * 64 + (((kk * 4 + g4) ^ (row & 7)) * 8)];
  };
  auto rdB = [&](const bf16* Bx, int nf, int kk) -> bf16x8 {
    int row = wn * 64 + nf * 16 + r16;
    return *(const bf16x8*)&Bx[row * 64 + (((kk * 4 + g4) ^ (row & 7)) * 8)];
  };

  stageA(0); stageB(0);
  asm volatile("s_waitcnt vmcnt(0)" ::: "memory");
  __builtin_amdgcn_s_barrier();

  for (int k = 0; k < NT; ++k) {
    const bf16* Ax = &Ab[k & 1][0];
    const bf16* Bx = &Bb[k & 1][0];
    bf16x8 aL[4], aH[4], bL[4];

#pragma unroll
    for (int mf = 0; mf < 4; ++mf) aL[mf] = rdA(Ax, mf, 0);
#pragma unroll
    for (int nf = 0; nf < 4; ++nf) bL[nf] = rdB(Bx, nf, 0);
#pragma unroll
    for (int mf = 0; mf < 4; ++mf) aH[mf] = rdA(Ax, 4 + mf, 0);
    if (k + 1 < NT) stageA(k + 1);
    __builtin_amdgcn_sched_barrier(0);

    __builtin_amdgcn_s_setprio(1);
#pragma unroll
    for (int mf = 0; mf < 4; ++mf)
#pragma unroll
      for (int nf = 0; nf < 4; ++nf)
        acc[mf][nf] = __builtin_amdgcn_mfma_f32_16x16x32_bf16(aL[mf], bL[nf], acc[mf][nf], 0, 0, 0);
    __builtin_amdgcn_s_setprio(0);

    bf16x8 aL2[4], bL2[4];
#pragma unroll
    for (int mf = 0; mf < 4; ++mf) aL2[mf] = rdA(Ax, mf, 1);
#pragma unroll
    for (int nf = 0; nf < 4; ++nf) bL2[nf] = rdB(Bx, nf, 1);
    if (k + 1 < NT) stageB(k + 1);
    __builtin_amdgcn_sched_barrier(0);

    __builtin_amdgcn_s_setprio(1);
#pragma unroll
    for (int mf = 0; mf < 4; ++mf)
#pragma unroll
      for (int nf = 0; nf < 4; ++nf)
        acc[4 + mf][nf] = __builtin_amdgcn_mfma_f32_16x16x32_bf16(aH[mf], bL[nf], acc[4 + mf][nf], 0, 0, 0);
    __builtin_amdgcn_s_setprio(0);

#pragma unroll
    for (int mf = 0; mf < 4; ++mf) aH[mf] = rdA(Ax, 4 + mf, 1);

    __builtin_amdgcn_s_setprio(1);
#pragma unroll
    for (int mf = 0; mf < 4; ++mf)
#pragma unroll
      for (int nf = 0; nf < 4; ++nf)
        acc[mf][nf] = __builtin_amdgcn_mfma_f32_16x16x32_bf16(aL2[mf], bL2[nf], acc[mf][nf], 0, 0, 0);

#pragma unroll
    for (int mf = 0; mf < 4; ++mf)
#pragma unroll
      for (int nf = 0; nf < 4; ++nf)
        acc[4 + mf][nf] = __builtin_amdgcn_mfma_f32_16x16x32_bf16(aH[mf], bL2[nf], acc[4 + mf][nf], 0, 0, 0);
    __builtin_amdgcn_s_setprio(0);

    if (k + 1 < NT) {
      asm volatile("s_waitcnt vmcnt(0)" ::: "memory");
      __builtin_amdgcn_s_barrier();
    }
  }

  // ---- epilogue
  if (z == 2) {
#pragma unroll
    for (int nf = 0; nf < 4; ++nf) {
      int n = n0 + wn * 64 + nf * 16 + r16;
      float bv = bias[n];
#pragma unroll
      for (int mf = 0; mf < 8; ++mf) {
        int mbase = m0 + wm * 128 + mf * 16 + g4 * 4;
        if (mbase < M) {
          bf16x4 o;
#pragma unroll
          for (int r = 0; r < 4; ++r) o[r] = (bf16)(acc[mf][nf][r] + bv);
          *(bf16x4*)&out[(size_t)n * MALL + mbase] = o;
        }
      }
    }
  } else {
#pragma unroll
    for (int nf = 0; nf < 4; ++nf) {
      int n = n0 + wn * 64 + nf * 16 + r16;
      float bv = bias[n];
#pragma unroll
      for (int mf = 0; mf < 8; ++mf) {
        int mbase = m0 + wm * 128 + mf * 16 + g4 * 4;
#pragma unroll
        for (int r = 0; r < 4; ++r) {
          int m = mbase + r;
          if (m < M) out[(size_t)m * DIMN + n] = (bf16)(acc[mf][nf][r] + bv);
        }
      }
    }
  }
}

// ---------------------------------------------------------------- key slot -> global row map (band paths)
__device__ __forceinline__ int key_row_map(int qb, int tslot) {
  if (qb <= 1) return tslot;                                    // rows 0..255
  if (qb == 63) return (tslot < 64) ? tslot : (3840 + tslot);   // block0 then blocks 61..63
  return (tslot < 64) ? tslot : ((qb - 1) * 64 + (tslot - 64)); // block0 + 3-block window
}

// ---------------------------------------------------------------- fused attention — deep prefetch.
// Flat 512-block grid, h=bid&7. 4 waves x 16 queries. ALL 5 K chunks staged up front into
// 80KB LDS (20 gload_lds/thread, counted waits vmcnt(16) — issue-position-invariant since
// newer-than-Kc = K(c+1..4)+V(0..c-1) = 16 always). V chunk j restages region j right after
// QK-j's closing barrier; PV-j waits vmcnt(4*(4-j)). One latency front instead of ten.
__global__ __launch_bounds__(256) void attn_kernel(
    const bf16* __restrict__ Q, const bf16* __restrict__ K, const bf16* __restrict__ VT,
    const float* __restrict__ mask, float* __restrict__ out) {
  const int bid = blockIdx.x;
  const int h = bid & 7, qb = bid >> 3;
  const int t = threadIdx.x;
  const int lane = t & 63, w = t >> 6;
  const int c16 = lane & 15, g4 = lane >> 4;
  const float sl = exp2f(-(float)(h + 1));
  const float rsq = 0.088388347648318447f;  // 1/sqrt(128)

  __shared__ bf16 KV[5 * 8192];  // 80 KiB: region c = K chunk c, later reused as V chunk c
  __shared__ bf16 P[64][328];    // band P cols 0..255, packed P cols 256..319 (+8 pad)

  // --- qf + mask loads FIRST (oldest in vmcnt queue), pinned by sched_barrier.
  bf16x8 qf[4];
  {
    int srow = qb * 64 + w * 16 + c16;
    const bf16* qp = Q + (size_t)srow * DIMN + h * HD + g4 * 8;
#pragma unroll
    for (int ks = 0; ks < 4; ++ks) qf[ks] = *(const bf16x8*)(qp + ks * 32);
  }
  int iq[4]; float mi[4];
#pragma unroll
  for (int r = 0; r < 4; ++r) { iq[r] = qb * 64 + w * 16 + g4 * 4 + r; mi[r] = mask[iq[r]]; }
  __builtin_amdgcn_sched_barrier(0);

  const bf16* vt_h = VT + (size_t)h * HD * MALL;

  auto stageK = [&](int c) {    // K chunk c: [64 rows][128], 4 gloads/thread, XOR-swizzled src
#pragma unroll
    for (int i = 0; i < 4; ++i) {
      int segBase = i * 256 + w * 64;
      int seg = segBase + lane;
      int kr = seg >> 4;
      int cc = (seg & 15) ^ (kr & 7);
      int gr = (c == 4) ? (SEQ + kr) : key_row_map(qb, c * 64 + kr);
      __builtin_amdgcn_global_load_lds(
          (gvoid_t*)(K + (size_t)gr * DIMN + h * HD + cc * 8),
          (lvoid_t*)(&KV[c * 8192 + segBase * 8]), 16, 0, 0);
    }
  };
  auto stageV = [&](int j) {    // V^T slab j: [128 d-rows][64 cols], into region j
    int colbase = (j == 4) ? SEQ : key_row_map(qb, j * 64);   // 64 contiguous rows in all cases
#pragma unroll
    for (int i = 0; i < 4; ++i) {
      int segBase = i * 256 + w * 64;
      int seg = segBase + lane;
      int dr = seg >> 3;
      int cc = (seg & 7) ^ (dr & 7);
      __builtin_amdgcn_global_load_lds(
          (gvoid_t*)(vt_h + (size_t)dr * MALL + colbase + cc * 8),
          (lvoid_t*)(&KV[j * 8192 + segBase * 8]), 16, 0, 0);
    }
  };

  // ---- stage ALL K chunks (20 loads/thread in flight)
#pragma unroll
  for (int c = 0; c < 5; ++c) stageK(c);

  f32x4 sc[16] = {};
  f32x4 sp[4] = {};

  // ---- QK^T: per chunk wait vmcnt(16) (exact; see header), barrier, 16 MFMA, barrier, stage V.
#pragma unroll
  for (int c = 0; c < 5; ++c) {
    asm volatile("s_waitcnt vmcnt(16)" ::: "memory");
    __builtin_amdgcn_s_barrier();                 // all waves' K-c slices landed
    const bf16* Kx = &KV[c * 8192];
#pragma unroll
    for (int ks = 0; ks < 4; ++ks)
#pragma unroll
      for (int kj = 0; kj < 4; ++kj) {
        int row = kj * 16 + c16;
        bf16x8 bfr = *(const bf16x8*)&Kx[row * 128 + (((ks * 4 + g4) ^ (row & 7)) * 8)];
        if (c < 4)
          sc[c * 4 + kj] = __builtin_amdgcn_mfma_f32_16x16x32_bf16(qf[ks], bfr, sc[c * 4 + kj], 0, 0, 0);
        else
          sp[kj] = __builtin_amdgcn_mfma_f32_16x16x32_bf16(qf[ks], bfr, sp[kj], 0, 0, 0);
      }
    __builtin_amdgcn_s_barrier();                 // all waves done reading region c
    stageV(c);                                    // overwrite region c with V slab c
  }

  // ---- bias (distance + mask penalties) — replicates reference quirks exactly
#pragma unroll
  for (int f = 0; f < 16; ++f) {
    int tslot = f * 16 + c16;
    int jrow = key_row_map(qb, tslot);
    float mj = mask[jrow];
    int jpos = (qb == 63) ? (3840 + tslot) : jrow;
    int ishift = (qb >= 2 && qb <= 62) ? 128 : 0;
#pragma unroll
    for (int r = 0; r < 4; ++r) {
      float raw = sc[f][r];
      float dist = sl * fabsf((float)(iq[r] - ishift - jpos));
      float s;
      if (qb <= 1)       s = raw * rsq - dist + (1.f - mi[r]) * PENV;
      else if (qb == 63) s = raw * rsq - dist;
      else {
        float pen = (tslot < 64) ? (1.f - mi[r]) * PENV : (1.f - mi[r] * mj) * PENV;
        s = (raw + pen) * rsq - dist;
      }
      sc[f][r] = s;
    }
  }

  // ---- band softmax (256 keys) -> P cols 0..255 (wave-private rows)
#pragma unroll
  for (int r = 0; r < 4; ++r) {
    float m = -1e30f;
#pragma unroll
    for (int f = 0; f < 16; ++f) m = fmaxf(m, sc[f][r]);
#pragma unroll
    for (int d = 1; d < 16; d <<= 1) m = fmaxf(m, __shfl_xor(m, d));
    float s = 0.f;
#pragma unroll
    for (int f = 0; f < 16; ++f) { float e = __expf(sc[f][r] - m); sc[f][r] = e; s += e; }
#pragma unroll
    for (int d = 1; d < 16; d <<= 1) s += __shfl_xor(s, d);
    float inv = 1.0f / s;
#pragma unroll
    for (int f = 0; f < 16; ++f)
      P[w * 16 + g4 * 4 + r][f * 16 + c16] = (bf16)(sc[f][r] * inv);
  }
  // ---- packed softmax (64 keys; constants cancel) -> P cols 256..319
#pragma unroll
  for (int r = 0; r < 4; ++r) {
    float m = -1e30f;
#pragma unroll
    for (int kj = 0; kj < 4; ++kj) m = fmaxf(m, sp[kj][r] * rsq);
#pragma unroll
    for (int d = 1; d < 16; d <<= 1) m = fmaxf(m, __shfl_xor(m, d));
    float s = 0.f;
    float e[4];
#pragma unroll
    for (int kj = 0; kj < 4; ++kj) { e[kj] = __expf(sp[kj][r] * rsq - m); s += e[kj]; }
#pragma unroll
    for (int d = 1; d < 16; d <<= 1) s += __shfl_xor(s, d);
    float inv = mi[r] / s;  // packed context pre-scaled by mask_v
#pragma unroll
    for (int kj = 0; kj < 4; ++kj)
      P[w * 16 + g4 * 4 + r][256 + kj * 16 + c16] = (bf16)(e[kj] * inv);
  }

  // ---- PV: 5 chunks; wait vmcnt(4*(4-j)) then barrier (all waves' V-j landed); no trailing
  //      barriers needed (regions never rewritten; P is wave-private).
  f32x4 ctx[8] = {};
#pragma unroll
  for (int j = 0; j < 5; ++j) {
    switch (j) {
      case 0: asm volatile("s_waitcnt vmcnt(16)" ::: "memory"); break;
      case 1: asm volatile("s_waitcnt vmcnt(12)" ::: "memory"); break;
      case 2: asm volatile("s_waitcnt vmcnt(8)"  ::: "memory"); break;
      case 3: asm volatile("s_waitcnt vmcnt(4)"  ::: "memory"); break;
      case 4: asm volatile("s_waitcnt vmcnt(0)"  ::: "memory"); break;
    }
    __builtin_amdgcn_s_barrier();
    const bf16* Vx = &KV[j * 8192];
    int pcol = (j < 4) ? j * 64 : 256;
#pragma unroll
    for (int ks = 0; ks < 2; ++ks) {
      bf16x8 pa = *(const bf16x8*)&P[w * 16 + c16][pcol + ks * 32 + g4 * 8];
#pragma unroll
      for (int df = 0; df < 8; ++df) {
        int row = df * 16 + c16;
        bf16x8 bv = *(const bf16x8*)&Vx[row * 64 + (((ks * 4 + g4) ^ (row & 7)) * 8)];
        ctx[df] = __builtin_amdgcn_mfma_f32_16x16x32_bf16(pa, bv, ctx[df], 0, 0, 0);
      }
    }
  }

  // ---- output: raw [H,S,hd] flatten; final mask uses reshaped-row quirk mask[h*512 + s/8]
#pragma unroll
  for (int df = 0; df < 8; ++df) {
    int d = df * 16 + c16;
#pragma unroll
    for (int r = 0; r < 4; ++r) {
      int s = iq[r];
      float fm = mask[h * 512 + (s >> 3)];
      out[(size_t)h * (SEQ * HD) + (size_t)s * HD + d] = ctx[df][r] * fm;
    }
  }
}

// ---------------------------------------------------------------- launch
extern "C" void kernel_launch(void* const* d_in, const int* in_sizes, int n_in,
                              void* d_out, int out_size, void* d_ws, size_t ws_size,
                              hipStream_t stream) {
  const float* X    = (const float*)d_in[0];
  const float* Cp   = (const float*)d_in[1];
  const float* mask = (const float*)d_in[2];
  const float* WQ   = (const float*)d_in[3];
  const float* bQ   = (const float*)d_in[4];
  const float* WK   = (const float*)d_in[5];
  const float* bK   = (const float*)d_in[6];
  const float* WV   = (const float*)d_in[7];
  const float* bV   = (const float*)d_in[8];
  float* out = (float*)d_out;

  bf16* Abf = (bf16*)d_ws;                              // [4160][1024]
  bf16* Wt  = Abf + (size_t)MALL * DIMN;                // 3 x [1024][1024] (transposed)
  bf16* QKV = Wt + (size_t)3 * DIMN * DIMN;             // q[4160][1024], k[4160][1024], VT[1024][4160]

  int nCvt = (MALL * DIMN / 4 + 255) / 256;
  cvt_cat_kernel<<<nCvt, 256, 0, stream>>>(X, Cp, Abf);
  cvt_trans_kernel<<<dim3(16, 16, 3), 256, 0, stream>>>(WQ, WK, WV, Wt);
  gemm_qkv_kernel<<<dim3(4, 17, 3), 512, 0, stream>>>(Abf, Wt, bQ, bK, bV, QKV);
  attn_kernel<<<512, 256, 0, stream>>>(QKV, QKV + (size_t)MALL * DIMN,
                                       QKV + (size_t)2 * MALL * DIMN, mask, out);
}

// Round 10
// 76.314 us; speedup vs baseline: 1.2500x; 1.1741x over previous
//
#include <hip/hip_runtime.h>
#include <hip/hip_bf16.h>

typedef __bf16 bf16;
typedef __attribute__((ext_vector_type(4))) __bf16 bf16x4;
typedef __attribute__((ext_vector_type(8))) __bf16 bf16x8;
typedef __attribute__((ext_vector_type(4))) float f32x4;

#define SEQ   4096
#define DIMN  1024
#define NHEAD 8
#define HD    128
#define MALL  4160   /* 4096 X rows + 64 Cp rows */
#define PENV  -10000.0f
#define NT    16     /* K-tiles of 64 */
#define NCVT  4160   /* blocks for cvt part of prep */

typedef const __attribute__((address_space(1))) void gvoid_t;
typedef __attribute__((address_space(3))) void lvoid_t;

// ---------------------------------------------------------------- prep: fused {fp32->bf16 X++Cp} + {W transpose}
// blocks [0, NCVT): cvt; blocks [NCVT, NCVT+768): transpose (768 = 16x16x3).
__global__ __launch_bounds__(256) void prep_kernel(
    const float* __restrict__ X, const float* __restrict__ Cp,
    const float* __restrict__ W0, const float* __restrict__ W1, const float* __restrict__ W2,
    bf16* __restrict__ A, bf16* __restrict__ Wt) {
  const int bid = blockIdx.x;
  if (bid < NCVT) {
    size_t base = ((size_t)bid * 256 + threadIdx.x) * 4;
    const float* src = (base < (size_t)SEQ * DIMN) ? (X + base) : (Cp + (base - (size_t)SEQ * DIMN));
    float4 v = *(const float4*)src;
    bf16x4 o;
    o[0] = (bf16)v.x; o[1] = (bf16)v.y; o[2] = (bf16)v.z; o[3] = (bf16)v.w;
    *(bf16x4*)&A[base] = o;
  } else {
    int tid2 = bid - NCVT;
    int z = tid2 >> 8, rem = tid2 & 255;
    int by = rem >> 4, bx = rem & 15;
    const float* W = (z == 0) ? W0 : ((z == 1) ? W1 : W2);
    bf16* dst = Wt + (size_t)z * DIMN * DIMN;
    __shared__ bf16 tile[64][72];
    int k0 = by * 64, n0 = bx * 64;
    int tx = threadIdx.x & 63, ty = threadIdx.x >> 6;
#pragma unroll
    for (int r = ty; r < 64; r += 4)
      tile[tx][r] = (bf16)W[(size_t)(k0 + r) * DIMN + n0 + tx];
    __syncthreads();
#pragma unroll
    for (int r = ty; r < 64; r += 4)
      dst[(size_t)(n0 + r) * DIMN + k0 + tx] = tile[r][tx];
  }
}

// ---------------------------------------------------------------- fused QKV GEMM — R6 structure (best measured, frozen).
// 256^2 tile, BK=64, dbuf-2, XOR chunk swizzle (source+read), 4 pipelined sub-phases per tile.
// z = 0:Q [m][n], 1:K [m][n], 2:V stored TRANSPOSED VT[n][m].
__global__ __launch_bounds__(512) void gemm_qkv_kernel(
    const bf16* __restrict__ A, const bf16* __restrict__ Wt,
    const float* __restrict__ bQ, const float* __restrict__ bK, const float* __restrict__ bV,
    bf16* __restrict__ QKV) {
  const int z = blockIdx.z;
  const int M = (z == 0) ? SEQ : MALL;
  const int m0 = blockIdx.y * 256;
  if (m0 >= M) return;
  const int n0 = blockIdx.x * 256;
  const bf16* Wz = Wt + (size_t)z * DIMN * DIMN;
  const float* bias = (z == 0) ? bQ : ((z == 1) ? bK : bV);
  bf16* out = QKV + (size_t)z * MALL * DIMN;

  __shared__ bf16 Ab[2][256 * 64];
  __shared__ bf16 Bb[2][256 * 64];

  const int t = threadIdx.x;
  const int lane = t & 63, w = t >> 6;
  const int wm = w >> 2, wn = w & 3;
  const int r16 = lane & 15, g4 = lane >> 4;

  f32x4 acc[8][4] = {};

  auto stageA = [&](int k) {
    int b = k & 1;
#pragma unroll
    for (int i = 0; i < 4; ++i) {
      int segBase = i * 512 + w * 64;
      int seg = segBase + lane;
      int row = seg >> 3;
      int cc = (seg & 7) ^ (row & 7);
      int gm = m0 + row; gm = (gm < M) ? gm : (M - 1);
      __builtin_amdgcn_global_load_lds(
          (gvoid_t*)(A + (size_t)gm * DIMN + k * 64 + cc * 8),
          (lvoid_t*)(&Ab[b][segBase * 8]), 16, 0, 0);
    }
  };
  auto stageB = [&](int k) {
    int b = k & 1;
#pragma unroll
    for (int i = 0; i < 4; ++i) {
      int segBase = i * 512 + w * 64;
      int seg = segBase + lane;
      int row = seg >> 3;
      int cc = (seg & 7) ^ (row & 7);
      int gn = n0 + row;
      __builtin_amdgcn_global_load_lds(
          (gvoid_t*)(Wz + (size_t)gn * DIMN + k * 64 + cc * 8),
          (lvoid_t*)(&Bb[b][segBase * 8]), 16, 0, 0);
    }
  };

  auto rdA = [&](const bf16* Ax, int mf, int kk) -> bf16x8 {
    int row = wm * 128 + mf * 16 + r16;
    return *(const bf16x8*)&Ax[row * 64 + (((kk * 4 + g4) ^ (row & 7)) * 8)];
  };
  auto rdB = [&](const bf16* Bx, int nf, int kk) -> bf16x8 {
    int row = wn * 64 + nf * 16 + r16;
    return *(const bf16x8*)&Bx[row * 64 + (((kk * 4 + g4) ^ (row & 7)) * 8)];
  };

  stageA(0); stageB(0);
  asm volatile("s_waitcnt vmcnt(0)" ::: "memory");
  __builtin_amdgcn_s_barrier();

  for (int k = 0; k < NT; ++k) {
    const bf16* Ax = &Ab[k & 1][0];
    const bf16* Bx = &Bb[k & 1][0];
    bf16x8 aL[4], aH[4], bL[4];

#pragma unroll
    for (int mf = 0; mf < 4; ++mf) aL[mf] = rdA(Ax, mf, 0);
#pragma unroll
    for (int nf = 0; nf < 4; ++nf) bL[nf] = rdB(Bx, nf, 0);
#pragma unroll
    for (int mf = 0; mf < 4; ++mf) aH[mf] = rdA(Ax, 4 + mf, 0);
    if (k + 1 < NT) stageA(k + 1);
    __builtin_amdgcn_sched_barrier(0);

    __builtin_amdgcn_s_setprio(1);
#pragma unroll
    for (int mf = 0; mf < 4; ++mf)
#pragma unroll
      for (int nf = 0; nf < 4; ++nf)
        acc[mf][nf] = __builtin_amdgcn_mfma_f32_16x16x32_bf16(aL[mf], bL[nf], acc[mf][nf], 0, 0, 0);
    __builtin_amdgcn_s_setprio(0);

    bf16x8 aL2[4], bL2[4];
#pragma unroll
    for (int mf = 0; mf < 4; ++mf) aL2[mf] = rdA(Ax, mf, 1);
#pragma unroll
    for (int nf = 0; nf < 4; ++nf) bL2[nf] = rdB(Bx, nf, 1);
    if (k + 1 < NT) stageB(k + 1);
    __builtin_amdgcn_sched_barrier(0);

    __builtin_amdgcn_s_setprio(1);
#pragma unroll
    for (int mf = 0; mf < 4; ++mf)
#pragma unroll
      for (int nf = 0; nf < 4; ++nf)
        acc[4 + mf][nf] = __builtin_amdgcn_mfma_f32_16x16x32_bf16(aH[mf], bL[nf], acc[4 + mf][nf], 0, 0, 0);
    __builtin_amdgcn_s_setprio(0);

#pragma unroll
    for (int mf = 0; mf < 4; ++mf) aH[mf] = rdA(Ax, 4 + mf, 1);

    __builtin_amdgcn_s_setprio(1);
#pragma unroll
    for (int mf = 0; mf < 4; ++mf)
#pragma unroll
      for (int nf = 0; nf < 4; ++nf)
        acc[mf][nf] = __builtin_amdgcn_mfma_f32_16x16x32_bf16(aL2[mf], bL2[nf], acc[mf][nf], 0, 0, 0);

#pragma unroll
    for (int mf = 0; mf < 4; ++mf)
#pragma unroll
      for (int nf = 0; nf < 4; ++nf)
        acc[4 + mf][nf] = __builtin_amdgcn_mfma_f32_16x16x32_bf16(aH[mf], bL2[nf], acc[4 + mf][nf], 0, 0, 0);
    __builtin_amdgcn_s_setprio(0);

    if (k + 1 < NT) {
      asm volatile("s_waitcnt vmcnt(0)" ::: "memory");
      __builtin_amdgcn_s_barrier();
    }
  }

  // ---- epilogue
  if (z == 2) {
#pragma unroll
    for (int nf = 0; nf < 4; ++nf) {
      int n = n0 + wn * 64 + nf * 16 + r16;
      float bv = bias[n];
#pragma unroll
      for (int mf = 0; mf < 8; ++mf) {
        int mbase = m0 + wm * 128 + mf * 16 + g4 * 4;
        if (mbase < M) {
          bf16x4 o;
#pragma unroll
          for (int r = 0; r < 4; ++r) o[r] = (bf16)(acc[mf][nf][r] + bv);
          *(bf16x4*)&out[(size_t)n * MALL + mbase] = o;
        }
      }
    }
  } else {
#pragma unroll
    for (int nf = 0; nf < 4; ++nf) {
      int n = n0 + wn * 64 + nf * 16 + r16;
      float bv = bias[n];
#pragma unroll
      for (int mf = 0; mf < 8; ++mf) {
        int mbase = m0 + wm * 128 + mf * 16 + g4 * 4;
#pragma unroll
        for (int r = 0; r < 4; ++r) {
          int m = mbase + r;
          if (m < M) out[(size_t)m * DIMN + n] = (bf16)(acc[mf][nf][r] + bv);
        }
      }
    }
  }
}

// ---------------------------------------------------------------- key slot -> global row map (band paths)
__device__ __forceinline__ int key_row_map(int qb, int tslot) {
  if (qb <= 1) return tslot;                                    // rows 0..255
  if (qb == 63) return (tslot < 64) ? tslot : (3840 + tslot);   // block0 then blocks 61..63
  return (tslot < 64) ? tslot : ((qb - 1) * 64 + (tslot - 64)); // block0 + 3-block window
}

// ---------------------------------------------------------------- fused attention — R8 ring-2 pipeline.
// 73KB LDS -> 2 blocks/CU -> all 512 blocks in ONE round; co-resident block hides chunk stalls.
// 10-chunk counted-vmcnt ring: 0..4 = K tiles (QK^T), 5..9 = V^T slabs (PV). Softmax covers V0.
__global__ __launch_bounds__(256) void attn_kernel(
    const bf16* __restrict__ Q, const bf16* __restrict__ K, const bf16* __restrict__ VT,
    const float* __restrict__ mask, float* __restrict__ out) {
  const int bid = blockIdx.x;
  const int h = bid & 7, qb = bid >> 3;
  const int t = threadIdx.x;
  const int lane = t & 63, w = t >> 6;
  const int c16 = lane & 15, g4 = lane >> 4;
  const float sl = exp2f(-(float)(h + 1));
  const float rsq = 0.088388347648318447f;  // 1/sqrt(128)

  __shared__ bf16 KB[2][8192];   // 16 KiB ring buffers (K tile or V^T slab), swizzled contents
  __shared__ bf16 P[64][328];    // band P cols 0..255, packed P cols 256..319 (+8 pad)

  bf16x8 qf[4];
  {
    int srow = qb * 64 + w * 16 + c16;
    const bf16* qp = Q + (size_t)srow * DIMN + h * HD + g4 * 8;
#pragma unroll
    for (int ks = 0; ks < 4; ++ks) qf[ks] = *(const bf16x8*)(qp + ks * 32);
  }
  int iq[4]; float mi[4];
#pragma unroll
  for (int r = 0; r < 4; ++r) { iq[r] = qb * 64 + w * 16 + g4 * 4 + r; mi[r] = mask[iq[r]]; }

  const bf16* vt_h = VT + (size_t)h * HD * MALL;

  // Stage chunk c: 4 gloads/thread, 16 KiB. c<5: K rows; c>=5: V^T d-rows (j=c-5).
  auto stageC = [&](int c) {
    int b = c & 1;
    if (c < 5) {
#pragma unroll
      for (int i = 0; i < 4; ++i) {
        int segBase = i * 256 + w * 64;
        int seg = segBase + lane;
        int kr = seg >> 4;
        int cc = (seg & 15) ^ (kr & 7);   // source-side swizzle
        int gr = (c == 4) ? (SEQ + kr) : key_row_map(qb, c * 64 + kr);
        __builtin_amdgcn_global_load_lds(
            (gvoid_t*)(K + (size_t)gr * DIMN + h * HD + cc * 8),
            (lvoid_t*)(&KB[b][segBase * 8]), 16, 0, 0);
      }
    } else {
      int j = c - 5;
      int colbase = (j == 4) ? SEQ : key_row_map(qb, j * 64);  // 64 contiguous rows in all cases
#pragma unroll
      for (int i = 0; i < 4; ++i) {
        int segBase = i * 256 + w * 64;
        int seg = segBase + lane;
        int dr = seg >> 3;
        int cc = (seg & 7) ^ (dr & 7);
        __builtin_amdgcn_global_load_lds(
            (gvoid_t*)(vt_h + (size_t)dr * MALL + colbase + cc * 8),
            (lvoid_t*)(&KB[b][segBase * 8]), 16, 0, 0);
      }
    }
  };

  f32x4 sc[16] = {};
  f32x4 sp[4] = {};

  // ---- QK^T over 5 K-chunks (4 band + packed), distance-1 prefetch, counted vmcnt.
  stageC(0);
#pragma unroll
  for (int c = 0; c < 5; ++c) {
    stageC(c + 1);                                     // c=4 stages V0 -> covered by softmax
    asm volatile("s_waitcnt vmcnt(4)" ::: "memory");   // chunk c resident; c+1 flies
    __builtin_amdgcn_s_barrier();
    const bf16* Kx = &KB[c & 1][0];
#pragma unroll
    for (int ks = 0; ks < 4; ++ks)
#pragma unroll
      for (int kj = 0; kj < 4; ++kj) {
        int row = kj * 16 + c16;
        bf16x8 bfr = *(const bf16x8*)&Kx[row * 128 + (((ks * 4 + g4) ^ (row & 7)) * 8)];
        if (c < 4)
          sc[c * 4 + kj] = __builtin_amdgcn_mfma_f32_16x16x32_bf16(qf[ks], bfr, sc[c * 4 + kj], 0, 0, 0);
        else
          sp[kj] = __builtin_amdgcn_mfma_f32_16x16x32_bf16(qf[ks], bfr, sp[kj], 0, 0, 0);
      }
    __builtin_amdgcn_s_barrier();   // all waves done reading KB[c&1] before restage
  }

  // ---- bias (distance + mask penalties) — replicates reference quirks exactly
#pragma unroll
  for (int f = 0; f < 16; ++f) {
    int tslot = f * 16 + c16;
    int jrow = key_row_map(qb, tslot);
    float mj = mask[jrow];
    int jpos = (qb == 63) ? (3840 + tslot) : jrow;
    int ishift = (qb >= 2 && qb <= 62) ? 128 : 0;
#pragma unroll
    for (int r = 0; r < 4; ++r) {
      float raw = sc[f][r];
      float dist = sl * fabsf((float)(iq[r] - ishift - jpos));
      float s;
      if (qb <= 1)       s = raw * rsq - dist + (1.f - mi[r]) * PENV;
      else if (qb == 63) s = raw * rsq - dist;
      else {
        float pen = (tslot < 64) ? (1.f - mi[r]) * PENV : (1.f - mi[r] * mj) * PENV;
        s = (raw + pen) * rsq - dist;
      }
      sc[f][r] = s;
    }
  }

  // ---- band softmax (256 keys) -> P cols 0..255 (wave-private rows)
#pragma unroll
  for (int r = 0; r < 4; ++r) {
    float m = -1e30f;
#pragma unroll
    for (int f = 0; f < 16; ++f) m = fmaxf(m, sc[f][r]);
#pragma unroll
    for (int d = 1; d < 16; d <<= 1) m = fmaxf(m, __shfl_xor(m, d));
    float s = 0.f;
#pragma unroll
    for (int f = 0; f < 16; ++f) { float e = __expf(sc[f][r] - m); sc[f][r] = e; s += e; }
#pragma unroll
    for (int d = 1; d < 16; d <<= 1) s += __shfl_xor(s, d);
    float inv = 1.0f / s;
#pragma unroll
    for (int f = 0; f < 16; ++f)
      P[w * 16 + g4 * 4 + r][f * 16 + c16] = (bf16)(sc[f][r] * inv);
  }
  // ---- packed softmax (64 keys; constants cancel) -> P cols 256..319
#pragma unroll
  for (int r = 0; r < 4; ++r) {
    float m = -1e30f;
#pragma unroll
    for (int kj = 0; kj < 4; ++kj) m = fmaxf(m, sp[kj][r] * rsq);
#pragma unroll
    for (int d = 1; d < 16; d <<= 1) m = fmaxf(m, __shfl_xor(m, d));
    float s = 0.f;
    float e[4];
#pragma unroll
    for (int kj = 0; kj < 4; ++kj) { e[kj] = __expf(sp[kj][r] * rsq - m); s += e[kj]; }
#pragma unroll
    for (int d = 1; d < 16; d <<= 1) s += __shfl_xor(s, d);
    float inv = mi[r] / s;  // packed context pre-scaled by mask_v
#pragma unroll
    for (int kj = 0; kj < 4; ++kj)
      P[w * 16 + g4 * 4 + r][256 + kj * 16 + c16] = (bf16)(e[kj] * inv);
  }

  // ---- PV over 5 V-chunks (4 band + packed) through the same ring.
  f32x4 ctx[8] = {};
#pragma unroll
  for (int j = 0; j < 5; ++j) {
    int c = j + 5;
    if (c < 9) {
      stageC(c + 1);
      asm volatile("s_waitcnt vmcnt(4)" ::: "memory");
    } else {
      asm volatile("s_waitcnt vmcnt(0)" ::: "memory");
    }
    __builtin_amdgcn_s_barrier();
    const bf16* Vx = &KB[c & 1][0];
    int pcol = (j < 4) ? j * 64 : 256;
#pragma unroll
    for (int ks = 0; ks < 2; ++ks) {
      bf16x8 pa = *(const bf16x8*)&P[w * 16 + c16][pcol + ks * 32 + g4 * 8];
#pragma unroll
      for (int df = 0; df < 8; ++df) {
        int row = df * 16 + c16;
        bf16x8 bv = *(const bf16x8*)&Vx[row * 64 + (((ks * 4 + g4) ^ (row & 7)) * 8)];
        ctx[df] = __builtin_amdgcn_mfma_f32_16x16x32_bf16(pa, bv, ctx[df], 0, 0, 0);
      }
    }
    __builtin_amdgcn_s_barrier();
  }

  // ---- output: raw [H,S,hd] flatten; final mask uses reshaped-row quirk mask[h*512 + s/8]
#pragma unroll
  for (int df = 0; df < 8; ++df) {
    int d = df * 16 + c16;
#pragma unroll
    for (int r = 0; r < 4; ++r) {
      int s = iq[r];
      float fm = mask[h * 512 + (s >> 3)];
      out[(size_t)h * (SEQ * HD) + (size_t)s * HD + d] = ctx[df][r] * fm;
    }
  }
}

// ---------------------------------------------------------------- launch
extern "C" void kernel_launch(void* const* d_in, const int* in_sizes, int n_in,
                              void* d_out, int out_size, void* d_ws, size_t ws_size,
                              hipStream_t stream) {
  const float* X    = (const float*)d_in[0];
  const float* Cp   = (const float*)d_in[1];
  const float* mask = (const float*)d_in[2];
  const float* WQ   = (const float*)d_in[3];
  const float* bQ   = (const float*)d_in[4];
  const float* WK   = (const float*)d_in[5];
  const float* bK   = (const float*)d_in[6];
  const float* WV   = (const float*)d_in[7];
  const float* bV   = (const float*)d_in[8];
  float* out = (float*)d_out;

  bf16* Abf = (bf16*)d_ws;                              // [4160][1024]
  bf16* Wt  = Abf + (size_t)MALL * DIMN;                // 3 x [1024][1024] (transposed)
  bf16* QKV = Wt + (size_t)3 * DIMN * DIMN;             // q[4160][1024], k[4160][1024], VT[1024][4160]

  prep_kernel<<<NCVT + 768, 256, 0, stream>>>(X, Cp, WQ, WK, WV, Abf, Wt);
  gemm_qkv_kernel<<<dim3(4, 17, 3), 512, 0, stream>>>(Abf, Wt, bQ, bK, bV, QKV);
  attn_kernel<<<512, 256, 0, stream>>>(QKV, QKV + (size_t)MALL * DIMN,
                                       QKV + (size_t)2 * MALL * DIMN, mask, out);
}